// Round 7
// baseline (957.599 us; speedup 1.0000x reference)
//
#include <hip/hip_runtime.h>
#include <hip/hip_bf16.h>
#include <math.h>

#define NB 32768
#define DIM 512
#define KF 8
#define FEAT 8192
#define BM 128
#define BK 64
#define NSTEP (FEAT / BK)   // 128

typedef __attribute__((ext_vector_type(8))) short bf16x8;
typedef __attribute__((ext_vector_type(4))) float f32x4;
typedef unsigned short ushort_t;
typedef unsigned int uint_t;

static __device__ __forceinline__ ushort_t f2bf_s(float f) {        // scalar bf16 (round-half-up)
    return (ushort_t)((__float_as_uint(f) + 0x8000u) >> 16);
}
static __device__ __forceinline__ float bf2f(ushort_t u) {
    return __uint_as_float(((uint_t)u) << 16);
}
// pack two floats -> one u32 holding 2 bf16 (round-half-up; sin/cos never NaN/Inf)
static __device__ __forceinline__ uint_t pk2(float a, float b) {
    return ((__float_as_uint(a) + 0x8000u) >> 16) | ((__float_as_uint(b) + 0x8000u) & 0xffff0000u);
}

// ---------------- pack A,B (fp32 [512][512][8]) -> Wt bf16 [512][8192] ----------------
// Wt[o][i*16 + j] = A[o][i][j] (j<8), B[o][i][j-8] (j>=8)
__global__ void pack_w(const float* __restrict__ A, const float* __restrict__ B,
                       ushort_t* __restrict__ Wt) {
    int idx = blockIdx.x * 256 + threadIdx.x;
    int o = idx >> 9, i = idx & 511;
    const float* a = A + ((size_t)o * DIM + i) * KF;
    const float* b = B + ((size_t)o * DIM + i) * KF;
    bf16x8 v0, v1;
#pragma unroll
    for (int j = 0; j < 8; ++j) {
        v0[j] = (short)f2bf_s(a[j]);
        v1[j] = (short)f2bf_s(b[j]);
    }
    ushort_t* dst = Wt + (size_t)o * FEAT + i * 16;
    *(bf16x8*)dst = v0;
    *(bf16x8*)(dst + 8) = v1;
}

// ---------------- layer 0: in=1 -> out=512 (bf16 activations out) ----------------
__global__ void layer0(const float* __restrict__ x, const float* __restrict__ A0,
                       const float* __restrict__ B0, ushort_t* __restrict__ Y) {
    int gid = blockIdx.x * 256 + threadIdx.x;
    int b = gid >> 9, o = gid & 511;
    float xv = x[b];
    float s1, c1;
    __sincosf(xv, &s1, &c1);
    const float* a = A0 + o * KF;
    const float* bb = B0 + o * KF;
    float acc = bb[0];
    float sk = 0.f, ck = 1.f;
#pragma unroll
    for (int k = 1; k < KF; ++k) {
        float sn = sk * c1 + ck * s1;
        float cn = ck * c1 - sk * s1;
        sk = sn; ck = cn;
        acc += a[k] * sk + bb[k] * ck;
    }
    Y[gid] = f2bf_s(acc);
}

// ---------------- fused feature+GEMM: Y = F(X)[N][8192] * Wt[512][8192]^T, bf16 in/out ----------------
// B-fragments loaded straight from global (L2) into registers — B never touches LDS.
// Wave grid 1x8: wave tile 128 rows x 64 cols; 8 waves cover all 512 cols, zero B duplication.
// LDS holds only the computed A-features (2 x 16 KB ping-pong, XOR-swizzled).
// One raw s_barrier per K-step with lgkmcnt(0) only — vmcnt is NEVER drained, so B loads
// and x-prefetch stay in flight across barriers.
__global__ __launch_bounds__(512, 2) void fkan_gemm(const ushort_t* __restrict__ X,
                                                    const ushort_t* __restrict__ Wt,
                                                    ushort_t* __restrict__ Y) {
    __shared__ ushort_t Alds[2][BM * BK];   // 2 x 16 KB
    const int tid = threadIdx.x;
    const int lane = tid & 63, wave = tid >> 6;
    const int l15 = lane & 15, l4 = lane >> 4;
    const int bm0 = blockIdx.x * BM;

    // A feature staging: one (row, input) item per thread per step
    const int bl = tid >> 2, ii = tid & 3;
    const ushort_t* xp = X + (size_t)(bm0 + bl) * DIM + ii;
    const int au0 = (((ii * 2) ^ (bl & 7)) * 8) + bl * BK;
    const int au1 = (((ii * 2 + 1) ^ (bl & 7)) * 8) + bl * BK;

    // A-fragment LDS read offsets (rows m*16+l15, swizzled unit)
    int aoff[8];
#pragma unroll
    for (int m = 0; m < 8; ++m) aoff[m] = (m * 16 + l15) * BK;
    const int up0 = ((l4) ^ (l15 & 7)) * 8;
    const int up1 = ((4 + l4) ^ (l15 & 7)) * 8;

    // B-fragment global pointers: col = wave*64 + n*16 + l15, k-offset l4*8 (+ kk*32 + t*64)
    const ushort_t* bbase[4];
#pragma unroll
    for (int n = 0; n < 4; ++n)
        bbase[n] = Wt + (size_t)(wave * 64 + n * 16 + l15) * FEAT + l4 * 8;

    f32x4 acc[8][4];
#pragma unroll
    for (int m = 0; m < 8; ++m)
#pragma unroll
        for (int n = 0; n < 4; ++n) acc[m][n] = (f32x4)0.f;

    // ---- prologue: features(0) -> Alds[0]; xv for features(1) ----
    {
        float xv0 = bf2f(xp[0]);
        float s1, c1;
        __sincosf(xv0, &s1, &c1);
        float s[KF], c[KF];
        s[0] = 0.f; c[0] = 1.f; s[1] = s1; c[1] = c1;
#pragma unroll
        for (int k = 2; k < KF; ++k) {
            s[k] = s[k - 1] * c1 + c[k - 1] * s1;
            c[k] = c[k - 1] * c1 - s[k - 1] * s1;
        }
        uint4 vs = { pk2(s[0], s[1]), pk2(s[2], s[3]), pk2(s[4], s[5]), pk2(s[6], s[7]) };
        uint4 vc = { pk2(c[0], c[1]), pk2(c[2], c[3]), pk2(c[4], c[5]), pk2(c[6], c[7]) };
        *(uint4*)&Alds[0][au0] = vs;
        *(uint4*)&Alds[0][au1] = vc;
    }
    float xv = bf2f(xp[4]);
    asm volatile("s_waitcnt lgkmcnt(0)" ::: "memory");
    __builtin_amdgcn_s_barrier();

    for (int t = 0; t < NSTEP; ++t) {
        const int cur = t & 1, nxt = cur ^ 1;
        const ushort_t* Ab = &Alds[cur][0];

        // ---- issue all 8 B-fragment loads for this step (L2-resident weights) ----
        bf16x8 b0[4], b1[4];
#pragma unroll
        for (int n = 0; n < 4; ++n) b0[n] = *(const bf16x8*)(bbase[n] + t * BK);
#pragma unroll
        for (int n = 0; n < 4; ++n) b1[n] = *(const bf16x8*)(bbase[n] + t * BK + 32);

        // ---- A-frags kk=0 from LDS ----
        bf16x8 af0[8];
#pragma unroll
        for (int m = 0; m < 8; ++m) af0[m] = *(const bf16x8*)&Ab[aoff[m] + up0];

        // ---- features(t+1) on VALU (covers B-load L2 latency) ----
        if (t + 1 < NSTEP) {
            float s1, c1;
            __sincosf(xv, &s1, &c1);
            float s[KF], c[KF];
            s[0] = 0.f; c[0] = 1.f; s[1] = s1; c[1] = c1;
#pragma unroll
            for (int k = 2; k < KF; ++k) {
                s[k] = s[k - 1] * c1 + c[k - 1] * s1;
                c[k] = c[k - 1] * c1 - s[k - 1] * s1;
            }
            uint4 vs = { pk2(s[0], s[1]), pk2(s[2], s[3]), pk2(s[4], s[5]), pk2(s[6], s[7]) };
            uint4 vc = { pk2(c[0], c[1]), pk2(c[2], c[3]), pk2(c[4], c[5]), pk2(c[6], c[7]) };
            *(uint4*)&Alds[nxt][au0] = vs;
            *(uint4*)&Alds[nxt][au1] = vc;
            if (t + 2 < NSTEP) xv = bf2f(xp[(t + 2) * 4]);   // stays in flight across barrier
        }

        // ---- MFMA kk=0 (32) ----
#pragma unroll
        for (int m = 0; m < 8; ++m)
#pragma unroll
            for (int n = 0; n < 4; ++n)
                acc[m][n] = __builtin_amdgcn_mfma_f32_16x16x32_bf16(af0[m], b0[n], acc[m][n], 0, 0, 0);

        // ---- A-frags kk=1 + MFMA kk=1 (32) ----
        bf16x8 af1[8];
#pragma unroll
        for (int m = 0; m < 8; ++m) af1[m] = *(const bf16x8*)&Ab[aoff[m] + up1];
#pragma unroll
        for (int m = 0; m < 8; ++m)
#pragma unroll
            for (int n = 0; n < 4; ++n)
                acc[m][n] = __builtin_amdgcn_mfma_f32_16x16x32_bf16(af1[m], b1[n], acc[m][n], 0, 0, 0);

        // ---- step boundary: only LDS drained; vmcnt (B/x loads) stays in flight ----
        asm volatile("s_waitcnt lgkmcnt(0)" ::: "memory");
        __builtin_amdgcn_s_barrier();
    }

    // ---- epilogue: C/D layout col=lane&15, row=(lane>>4)*4+reg; bf16 store ----
#pragma unroll
    for (int m = 0; m < 8; ++m)
#pragma unroll
        for (int n = 0; n < 4; ++n)
#pragma unroll
            for (int j = 0; j < 4; ++j) {
                int row = bm0 + m * 16 + l4 * 4 + j;
                int col = wave * 64 + n * 16 + l15;
                Y[(size_t)row * DIM + col] = f2bf_s(acc[m][n][j]);
            }
}

// ---------------- layer 4: in=512 -> out=1, one wave per row (bf16 X) ----------------
__global__ void layer4(const ushort_t* __restrict__ X, const float* __restrict__ A4,
                       const float* __restrict__ B4, float* __restrict__ Y) {
    int wave = threadIdx.x >> 6, lane = threadIdx.x & 63;
    int b = blockIdx.x * 4 + wave;
    float acc = 0.f;
#pragma unroll
    for (int ii = 0; ii < 8; ++ii) {
        int i = lane + ii * 64;
        float xv = bf2f(X[(size_t)b * DIM + i]);
        float s1, c1;
        __sincosf(xv, &s1, &c1);
        const float* a = A4 + i * KF;
        const float* bb = B4 + i * KF;
        acc += bb[0];
        float sk = 0.f, ck = 1.f;
#pragma unroll
        for (int k = 1; k < KF; ++k) {
            float sn = sk * c1 + ck * s1;
            float cn = ck * c1 - sk * s1;
            sk = sn; ck = cn;
            acc += a[k] * sk + bb[k] * ck;
        }
    }
#pragma unroll
    for (int off = 32; off > 0; off >>= 1) acc += __shfl_down(acc, off, 64);
    if (lane == 0) Y[b] = acc;
}

extern "C" void kernel_launch(void* const* d_in, const int* in_sizes, int n_in,
                              void* d_out, int out_size, void* d_ws, size_t ws_size,
                              hipStream_t stream) {
    const float* x  = (const float*)d_in[0];
    const float* A0 = (const float*)d_in[1];
    const float* B0 = (const float*)d_in[2];
    const float* A1 = (const float*)d_in[3];
    const float* B1 = (const float*)d_in[4];
    const float* A2 = (const float*)d_in[5];
    const float* B2 = (const float*)d_in[6];
    const float* A3 = (const float*)d_in[7];
    const float* B3 = (const float*)d_in[8];
    const float* A4 = (const float*)d_in[9];
    const float* B4 = (const float*)d_in[10];
    float* out = (float*)d_out;

    char* ws = (char*)d_ws;
    const size_t actBytes = (size_t)NB * DIM * sizeof(ushort_t);  // 32 MB (bf16 activations)
    ushort_t* bufA = (ushort_t*)ws;
    ushort_t* bufB = (ushort_t*)(ws + actBytes);
    ushort_t* W1 = (ushort_t*)(ws + 2 * actBytes);
    ushort_t* W2 = W1 + (size_t)DIM * FEAT;
    ushort_t* W3 = W2 + (size_t)DIM * FEAT;

    pack_w<<<DIM * DIM / 256, 256, 0, stream>>>(A1, B1, W1);
    pack_w<<<DIM * DIM / 256, 256, 0, stream>>>(A2, B2, W2);
    pack_w<<<DIM * DIM / 256, 256, 0, stream>>>(A3, B3, W3);

    layer0<<<(NB * DIM) / 256, 256, 0, stream>>>(x, A0, B0, bufA);

    fkan_gemm<<<NB / BM, 512, 0, stream>>>(bufA, W1, bufB);
    fkan_gemm<<<NB / BM, 512, 0, stream>>>(bufB, W2, bufA);
    fkan_gemm<<<NB / BM, 512, 0, stream>>>(bufA, W3, bufB);

    layer4<<<NB / 4, 256, 0, stream>>>(bufB, A4, B4, out);
}

// Round 8
// 749.183 us; speedup vs baseline: 1.2782x; 1.2782x over previous
//
#include <hip/hip_runtime.h>
#include <hip/hip_bf16.h>
#include <math.h>

#define NB 32768
#define DIM 512
#define KF 8
#define FEAT 8192
#define BM 128
#define BK 64
#define NSTEP (FEAT / BK)   // 128

typedef __attribute__((ext_vector_type(8))) short bf16x8;
typedef __attribute__((ext_vector_type(4))) float f32x4;
typedef unsigned short ushort_t;
typedef unsigned int uint_t;

static __device__ __forceinline__ ushort_t f2bf_s(float f) {        // scalar bf16 (round-half-up)
    return (ushort_t)((__float_as_uint(f) + 0x8000u) >> 16);
}
static __device__ __forceinline__ float bf2f(ushort_t u) {
    return __uint_as_float(((uint_t)u) << 16);
}
// pack two floats -> one u32 holding 2 bf16 (round-half-up; sin/cos never NaN/Inf)
static __device__ __forceinline__ uint_t pk2(float a, float b) {
    return ((__float_as_uint(a) + 0x8000u) >> 16) | ((__float_as_uint(b) + 0x8000u) & 0xffff0000u);
}

// ---------------- pack A,B (fp32 [512][512][8]) -> fragment-stream Wf (bf16) ----------------
// Wf[((((t*8+w)*2+kk)*4+n)*64+lane)*8 + e]:
//   o  = w*64 + n*16 + (lane&15)                  (output col)
//   kg = t*64 + kk*32 + (lane>>4)*8               (feature index; kg&15 is 0 or 8)
//   i  = kg>>4;  value = (kg&15)<8 ? A[o][i][e] : B[o][i][e]
// So a wave's B-fragment load for (t,kk,n) is a CONTIGUOUS 1KB block: base + lane*16.
__global__ void pack_w2(const float* __restrict__ A, const float* __restrict__ B,
                        ushort_t* __restrict__ Wf) {
    int u = blockIdx.x * 256 + threadIdx.x;       // 0 .. 524287 (16B units)
    int lane = u & 63;
    int n = (u >> 6) & 3, kk = (u >> 8) & 1, w = (u >> 9) & 7, t = u >> 12;
    int o = w * 64 + n * 16 + (lane & 15);
    int kg = t * 64 + kk * 32 + (lane >> 4) * 8;
    int i = kg >> 4;
    const float* src = ((kg & 15) < 8 ? A : B) + ((size_t)o * DIM + i) * KF;
    bf16x8 v;
#pragma unroll
    for (int e = 0; e < 8; ++e) v[e] = (short)f2bf_s(src[e]);
    *(bf16x8*)&Wf[(size_t)u * 8] = v;
}

// ---------------- layer 0: in=1 -> out=512 (bf16 activations out) ----------------
__global__ void layer0(const float* __restrict__ x, const float* __restrict__ A0,
                       const float* __restrict__ B0, ushort_t* __restrict__ Y) {
    int gid = blockIdx.x * 256 + threadIdx.x;
    int b = gid >> 9, o = gid & 511;
    float xv = x[b];
    float s1, c1;
    __sincosf(xv, &s1, &c1);
    const float* a = A0 + o * KF;
    const float* bb = B0 + o * KF;
    float acc = bb[0];
    float sk = 0.f, ck = 1.f;
#pragma unroll
    for (int k = 1; k < KF; ++k) {
        float sn = sk * c1 + ck * s1;
        float cn = ck * c1 - sk * s1;
        sk = sn; ck = cn;
        acc += a[k] * sk + bb[k] * ck;
    }
    Y[gid] = f2bf_s(acc);
}

// ---------------- fused feature+GEMM: Y = F(X)[N][8192] * W^T, bf16 in/out ----------------
// B-fragments register-streamed from fragment-order Wf (coalesced 1KB loads, no LDS for B,
// prefetched one step ahead). LDS holds only computed A-features (2 x 16 KB ping-pong,
// XOR-swizzled). One lgkmcnt(0)+s_barrier per step; vmcnt NEVER drained.
__global__ __launch_bounds__(512, 2) void fkan_gemm(const ushort_t* __restrict__ X,
                                                    const ushort_t* __restrict__ Wf,
                                                    ushort_t* __restrict__ Y) {
    __shared__ ushort_t Alds[2][BM * BK];   // 2 x 16 KB
    const int tid = threadIdx.x;
    const int lane = tid & 63, wave = tid >> 6;
    const int l15 = lane & 15, l4 = lane >> 4;
    const int bm0 = blockIdx.x * BM;

    // A feature staging: one (row, input) item per thread per step
    const int bl = tid >> 2, ii = tid & 3;
    const ushort_t* xp = X + (size_t)(bm0 + bl) * DIM + ii;
    const int au0 = (((ii * 2) ^ (bl & 7)) * 8) + bl * BK;
    const int au1 = (((ii * 2 + 1) ^ (bl & 7)) * 8) + bl * BK;

    // A-fragment LDS read offsets (wave tile 128 rows x 64 cols; 1x8 wave grid)
    int aoff[8];
#pragma unroll
    for (int m = 0; m < 8; ++m) aoff[m] = (m * 16 + l15) * BK;
    const int up0 = ((l4) ^ (l15 & 7)) * 8;
    const int up1 = ((4 + l4) ^ (l15 & 7)) * 8;

    // B fragment stream pointer: step t, (kk,n) at offsets t*32768 + kk*2048 + n*512
    const ushort_t* bp = Wf + wave * 4096 + lane * 8;

    f32x4 acc[8][4];
#pragma unroll
    for (int m = 0; m < 8; ++m)
#pragma unroll
        for (int n = 0; n < 4; ++n) acc[m][n] = (f32x4)0.f;

    // ---- prologue: features(0) -> Alds[0]; B(0) -> regs; xv for features(1) ----
    {
        float xv0 = bf2f(xp[0]);
        float s1, c1;
        __sincosf(xv0, &s1, &c1);
        float s[KF], c[KF];
        s[0] = 0.f; c[0] = 1.f; s[1] = s1; c[1] = c1;
#pragma unroll
        for (int k = 2; k < KF; ++k) {
            s[k] = s[k - 1] * c1 + c[k - 1] * s1;
            c[k] = c[k - 1] * c1 - s[k - 1] * s1;
        }
        uint4 vs = { pk2(s[0], s[1]), pk2(s[2], s[3]), pk2(s[4], s[5]), pk2(s[6], s[7]) };
        uint4 vc = { pk2(c[0], c[1]), pk2(c[2], c[3]), pk2(c[4], c[5]), pk2(c[6], c[7]) };
        *(uint4*)&Alds[0][au0] = vs;
        *(uint4*)&Alds[0][au1] = vc;
    }
    bf16x8 c0[4], c1[4];
#pragma unroll
    for (int n = 0; n < 4; ++n) c0[n] = *(const bf16x8*)(bp + n * 512);
#pragma unroll
    for (int n = 0; n < 4; ++n) c1[n] = *(const bf16x8*)(bp + 2048 + n * 512);
    float xv = bf2f(xp[4]);
    asm volatile("s_waitcnt lgkmcnt(0)" ::: "memory");
    __builtin_amdgcn_s_barrier();

    for (int t = 0; t < NSTEP; ++t) {
        const int cur = t & 1, nxt = cur ^ 1;
        const ushort_t* Ab = &Alds[cur][0];

        // ---- issue B(t+1) register prefetch (coalesced 1KB loads; stays in flight) ----
        bf16x8 p0[4], p1[4];
        if (t + 1 < NSTEP) {
            const ushort_t* bn = bp + (t + 1) * 32768;
#pragma unroll
            for (int n = 0; n < 4; ++n) p0[n] = *(const bf16x8*)(bn + n * 512);
#pragma unroll
            for (int n = 0; n < 4; ++n) p1[n] = *(const bf16x8*)(bn + 2048 + n * 512);
        }

        // ---- A-frags kk=0 ----
        bf16x8 af0[8];
#pragma unroll
        for (int m = 0; m < 8; ++m) af0[m] = *(const bf16x8*)&Ab[aoff[m] + up0];

        // ---- features(t+1) on VALU (covers B prefetch latency) ----
        if (t + 1 < NSTEP) {
            float s1, c1v;
            __sincosf(xv, &s1, &c1v);
            float s[KF], c[KF];
            s[0] = 0.f; c[0] = 1.f; s[1] = s1; c[1] = c1v;
#pragma unroll
            for (int k = 2; k < KF; ++k) {
                s[k] = s[k - 1] * c1v + c[k - 1] * s1;
                c[k] = c[k - 1] * c1v - s[k - 1] * s1;
            }
            uint4 vs = { pk2(s[0], s[1]), pk2(s[2], s[3]), pk2(s[4], s[5]), pk2(s[6], s[7]) };
            uint4 vc = { pk2(c[0], c[1]), pk2(c[2], c[3]), pk2(c[4], c[5]), pk2(c[6], c[7]) };
            *(uint4*)&Alds[nxt][au0] = vs;
            *(uint4*)&Alds[nxt][au1] = vc;
            if (t + 2 < NSTEP) xv = bf2f(xp[(t + 2) * 4]);
        }

        // ---- MFMA kk=0 (32) with current B regs ----
#pragma unroll
        for (int m = 0; m < 8; ++m)
#pragma unroll
            for (int n = 0; n < 4; ++n)
                acc[m][n] = __builtin_amdgcn_mfma_f32_16x16x32_bf16(af0[m], c0[n], acc[m][n], 0, 0, 0);

        // ---- A-frags kk=1 + MFMA kk=1 (32) ----
        bf16x8 af1[8];
#pragma unroll
        for (int m = 0; m < 8; ++m) af1[m] = *(const bf16x8*)&Ab[aoff[m] + up1];
#pragma unroll
        for (int m = 0; m < 8; ++m)
#pragma unroll
            for (int n = 0; n < 4; ++n)
                acc[m][n] = __builtin_amdgcn_mfma_f32_16x16x32_bf16(af1[m], c1[n], acc[m][n], 0, 0, 0);

        // ---- rotate prefetch regs; barrier drains only LDS (vmcnt stays in flight) ----
#pragma unroll
        for (int n = 0; n < 4; ++n) { c0[n] = p0[n]; c1[n] = p1[n]; }
        asm volatile("s_waitcnt lgkmcnt(0)" ::: "memory");
        __builtin_amdgcn_s_barrier();
    }

    // ---- epilogue: C/D layout col=lane&15, row=(lane>>4)*4+reg; bf16 store ----
#pragma unroll
    for (int m = 0; m < 8; ++m)
#pragma unroll
        for (int n = 0; n < 4; ++n)
#pragma unroll
            for (int j = 0; j < 4; ++j) {
                int row = bm0 + m * 16 + l4 * 4 + j;
                int col = wave * 64 + n * 16 + l15;
                Y[(size_t)row * DIM + col] = f2bf_s(acc[m][n][j]);
            }
}

// ---------------- layer 4: in=512 -> out=1, one wave per row (bf16 X) ----------------
__global__ void layer4(const ushort_t* __restrict__ X, const float* __restrict__ A4,
                       const float* __restrict__ B4, float* __restrict__ Y) {
    int wave = threadIdx.x >> 6, lane = threadIdx.x & 63;
    int b = blockIdx.x * 4 + wave;
    float acc = 0.f;
#pragma unroll
    for (int ii = 0; ii < 8; ++ii) {
        int i = lane + ii * 64;
        float xv = bf2f(X[(size_t)b * DIM + i]);
        float s1, c1;
        __sincosf(xv, &s1, &c1);
        const float* a = A4 + i * KF;
        const float* bb = B4 + i * KF;
        acc += bb[0];
        float sk = 0.f, ck = 1.f;
#pragma unroll
        for (int k = 1; k < KF; ++k) {
            float sn = sk * c1 + ck * s1;
            float cn = ck * c1 - sk * s1;
            sk = sn; ck = cn;
            acc += a[k] * sk + bb[k] * ck;
        }
    }
#pragma unroll
    for (int off = 32; off > 0; off >>= 1) acc += __shfl_down(acc, off, 64);
    if (lane == 0) Y[b] = acc;
}

extern "C" void kernel_launch(void* const* d_in, const int* in_sizes, int n_in,
                              void* d_out, int out_size, void* d_ws, size_t ws_size,
                              hipStream_t stream) {
    const float* x  = (const float*)d_in[0];
    const float* A0 = (const float*)d_in[1];
    const float* B0 = (const float*)d_in[2];
    const float* A1 = (const float*)d_in[3];
    const float* B1 = (const float*)d_in[4];
    const float* A2 = (const float*)d_in[5];
    const float* B2 = (const float*)d_in[6];
    const float* A3 = (const float*)d_in[7];
    const float* B3 = (const float*)d_in[8];
    const float* A4 = (const float*)d_in[9];
    const float* B4 = (const float*)d_in[10];
    float* out = (float*)d_out;

    char* ws = (char*)d_ws;
    const size_t actBytes = (size_t)NB * DIM * sizeof(ushort_t);  // 32 MB (bf16 activations)
    ushort_t* bufA = (ushort_t*)ws;
    ushort_t* bufB = (ushort_t*)(ws + actBytes);
    ushort_t* W1 = (ushort_t*)(ws + 2 * actBytes);
    ushort_t* W2 = W1 + (size_t)DIM * FEAT;
    ushort_t* W3 = W2 + (size_t)DIM * FEAT;

    pack_w2<<<DIM * FEAT / 8 / 256, 256, 0, stream>>>(A1, B1, W1);
    pack_w2<<<DIM * FEAT / 8 / 256, 256, 0, stream>>>(A2, B2, W2);
    pack_w2<<<DIM * FEAT / 8 / 256, 256, 0, stream>>>(A3, B3, W3);

    layer0<<<(NB * DIM) / 256, 256, 0, stream>>>(x, A0, B0, bufA);

    fkan_gemm<<<NB / BM, 512, 0, stream>>>(bufA, W1, bufB);
    fkan_gemm<<<NB / BM, 512, 0, stream>>>(bufB, W2, bufA);
    fkan_gemm<<<NB / BM, 512, 0, stream>>>(bufA, W3, bufB);

    layer4<<<NB / 4, 256, 0, stream>>>(bufB, A4, B4, out);
}